// Round 1
// baseline (215.731 us; speedup 1.0000x reference)
//
#include <hip/hip_runtime.h>
#include <hip/hip_bf16.h>

typedef __attribute__((ext_vector_type(4))) float f32x4;
typedef __attribute__((ext_vector_type(8))) short short8;

// ---------- helpers ----------
__device__ __forceinline__ unsigned short f2bf(float f) {
  unsigned int u = __float_as_uint(f);
  u += 0x7fffu + ((u >> 16) & 1u);   // RNE
  return (unsigned short)(u >> 16);
}

__device__ __forceinline__ void g2lds16(const void* g, void* l) {
  __builtin_amdgcn_global_load_lds(
      (const __attribute__((address_space(1))) void*)g,
      (__attribute__((address_space(3))) void*)l, 16, 0, 0);
}

// ---------- f32 -> bf16 convert ----------
__global__ __launch_bounds__(256) void cvt_bf16(const float* __restrict__ src,
                                                unsigned short* __restrict__ dst,
                                                int n4) {
  int i = blockIdx.x * 256 + threadIdx.x;
  if (i >= n4) return;
  const float4 v = ((const float4*)src)[i];
  ushort4 o;
  o.x = f2bf(v.x); o.y = f2bf(v.y); o.z = f2bf(v.z); o.w = f2bf(v.w);
  ((ushort4*)dst)[i] = o;
}

// ---------- mask -> bitmask ----------
__global__ __launch_bounds__(256) void pack_mask(const int* __restrict__ mask,
                                                 unsigned long long* __restrict__ mb) {
  int i = blockIdx.x * 256 + threadIdx.x;
  unsigned long long bits = __ballot(mask[i] != 0);
  if ((threadIdx.x & 63) == 0) mb[i >> 6] = bits;
}

// ---------- 128x128 tile bf16 GEMM: C[M,N] = A[M,K] @ B[N,K]^T (+bias) ----------
// BIAS_MODE: 0 none, 1 per-col(N), 2 per-row(M).  OUT_BF16: 1 bf16, 0 f32.
template <int BIAS_MODE, int OUT_BF16>
__device__ __forceinline__ void gemm_tile(
    unsigned short* __restrict__ As, unsigned short* __restrict__ Bs,
    const unsigned short* __restrict__ A, const unsigned short* __restrict__ B,
    const float* __restrict__ bias, void* __restrict__ Cp,
    const int N, const int K, const int m0, const int n0) {
  const int tid  = (int)threadIdx.x;
  const int lane = tid & 63;
  const int wm   = tid >> 7;
  const int wn   = (tid >> 6) & 1;

  const f32x4 vzero = {0.f, 0.f, 0.f, 0.f};
  f32x4 acc[4][4];
#pragma unroll
  for (int mr = 0; mr < 4; ++mr)
#pragma unroll
    for (int nr = 0; nr < 4; ++nr) acc[mr][nr] = vzero;

  for (int k0 = 0; k0 < K; k0 += 64) {
    // stage A,B tiles (128x64 bf16 each) via async global->LDS, width 16,
    // source pre-swizzled so LDS holds XOR(row&7)-swizzled 16B chunks.
#pragma unroll
    for (int i = 0; i < 4; ++i) {
      const int idx = i * 256 + tid;
      const int r = idx >> 3;
      const int c = idx & 7;
      const int koff = k0 + ((c ^ (r & 7)) << 3);
      g2lds16(A + (size_t)(m0 + r) * K + koff, &As[(i * 256 + (tid & 192)) * 8]);
      g2lds16(B + (size_t)(n0 + r) * K + koff, &Bs[(i * 256 + (tid & 192)) * 8]);
    }
    __syncthreads();
#pragma unroll
    for (int kk = 0; kk < 2; ++kk) {
      short8 af[4], bf[4];
#pragma unroll
      for (int mr = 0; mr < 4; ++mr) {
        const int row = wm * 64 + mr * 16 + (lane & 15);
        const int ch = (kk * 4 + (lane >> 4)) ^ (row & 7);
        af[mr] = *(const short8*)&As[row * 64 + ch * 8];
      }
#pragma unroll
      for (int nr = 0; nr < 4; ++nr) {
        const int row = wn * 64 + nr * 16 + (lane & 15);
        const int ch = (kk * 4 + (lane >> 4)) ^ (row & 7);
        bf[nr] = *(const short8*)&Bs[row * 64 + ch * 8];
      }
#pragma unroll
      for (int mr = 0; mr < 4; ++mr)
#pragma unroll
        for (int nr = 0; nr < 4; ++nr)
          acc[mr][nr] = __builtin_amdgcn_mfma_f32_16x16x32_bf16(af[mr], bf[nr],
                                                                acc[mr][nr], 0, 0, 0);
    }
    __syncthreads();
  }

#pragma unroll
  for (int mr = 0; mr < 4; ++mr) {
#pragma unroll
    for (int nr = 0; nr < 4; ++nr) {
#pragma unroll
      for (int rg = 0; rg < 4; ++rg) {
        const int row = m0 + wm * 64 + mr * 16 + ((lane >> 4) << 2) + rg;
        const int col = n0 + wn * 64 + nr * 16 + (lane & 15);
        float v = acc[mr][nr][rg];
        if (BIAS_MODE == 1) v += bias[col];
        if (BIAS_MODE == 2) v += bias[row];
        if (OUT_BF16) ((unsigned short*)Cp)[(size_t)row * N + col] = f2bf(v);
        else          ((float*)Cp)[(size_t)row * N + col] = v;
      }
    }
  }
}

// qp = xq@Wq^T+bq ; kp = xk@Wk^T+bk ; vt = Wv@xv^T+bv  (vt is [1024 d'][4096 tok])
__global__ __launch_bounds__(256) void proj_qkv(
    const unsigned short* __restrict__ xq, const unsigned short* __restrict__ xk,
    const unsigned short* __restrict__ xv,
    const unsigned short* __restrict__ wq, const unsigned short* __restrict__ wk,
    const unsigned short* __restrict__ wv,
    const float* __restrict__ bq, const float* __restrict__ bk,
    const float* __restrict__ bv,
    unsigned short* __restrict__ qp, unsigned short* __restrict__ kp,
    unsigned short* __restrict__ vt) {
  __shared__ unsigned short As[128 * 64];
  __shared__ unsigned short Bs[128 * 64];
  const int z = blockIdx.z;
  if (z == 0) {
    gemm_tile<1, 1>(As, Bs, xq, wq, bq, qp, 1024, 1024, blockIdx.y * 128, blockIdx.x * 128);
  } else if (z == 1) {
    gemm_tile<1, 1>(As, Bs, xk, wk, bk, kp, 1024, 1024, blockIdx.y * 128, blockIdx.x * 128);
  } else {
    gemm_tile<2, 1>(As, Bs, wv, xv, bv, vt, 4096, 1024, blockIdx.x * 128, blockIdx.y * 128);
  }
}

__global__ __launch_bounds__(256) void out_proj(
    const unsigned short* __restrict__ ao, const unsigned short* __restrict__ wo,
    float* __restrict__ out) {
  __shared__ unsigned short As[128 * 64];
  __shared__ unsigned short Bs[128 * 64];
  gemm_tile<0, 0>(As, Bs, ao, wo, nullptr, out, 1024, 1024, blockIdx.y * 128, blockIdx.x * 128);
}

// ---------- fused silu-attention ----------
// grid (32 qblk, 16 h, 2 b), 256 thr (4 waves x 16 q-rows). K/V tiles 64x64 in LDS.
__global__ __launch_bounds__(256) void attn_kernel(
    const unsigned short* __restrict__ qp, const unsigned short* __restrict__ kp,
    const unsigned short* __restrict__ vt, const unsigned int* __restrict__ mb,
    unsigned short* __restrict__ ao) {
  __shared__ unsigned short Ks[64 * 64];
  __shared__ unsigned short Vts[64 * 64];
  __shared__ unsigned short Ps[4 * 16 * 64];
  __shared__ unsigned int msk[128];

  const int tid  = (int)threadIdx.x;
  const int lane = tid & 63;
  const int w    = tid >> 6;
  const int qbase = blockIdx.x * 64;
  const int h = blockIdx.y;
  const int b = blockIdx.z;
  const size_t tok0 = (size_t)b * 2048;

  // Q fragments held in registers for the whole block
  const int qr = qbase + w * 16 + (lane & 15);
  const unsigned short* qptr = qp + (tok0 + qr) * 1024 + h * 64 + ((lane >> 4) << 3);
  const short8 aq0 = *(const short8*)qptr;
  const short8 aq1 = *(const short8*)(qptr + 32);

  const f32x4 vzero = {0.f, 0.f, 0.f, 0.f};
  f32x4 oacc[4];
#pragma unroll
  for (int nr = 0; nr < 4; ++nr) oacc[nr] = vzero;

  for (int kt = 0; kt < 32; ++kt) {
    // stage K tile [64 tok][64 d] and V^T tile [64 d][64 tok], source pre-swizzled
#pragma unroll
    for (int i = 0; i < 2; ++i) {
      const int idx = i * 256 + tid;
      const int r = idx >> 3;
      const int c = idx & 7;
      const int cs = (c ^ (r & 7)) << 3;
      g2lds16(kp + (tok0 + kt * 64 + r) * 1024 + h * 64 + cs,
              &Ks[(i * 256 + (tid & 192)) * 8]);
      g2lds16(vt + (size_t)(h * 64 + r) * 4096 + tok0 + kt * 64 + cs,
              &Vts[(i * 256 + (tid & 192)) * 8]);
    }
    if (tid < 128)
      msk[tid] = mb[(tok0 + qbase + (tid >> 1)) * 64 + kt * 2 + (tid & 1)];
    __syncthreads();

    // S = Q @ K^T  (per wave: 16 q-rows x 64 k-cols)
    f32x4 s[4];
#pragma unroll
    for (int nr = 0; nr < 4; ++nr) {
      const int krow = nr * 16 + (lane & 15);
      const short8 b0 = *(const short8*)&Ks[krow * 64 + (((lane >> 4)) ^ (krow & 7)) * 8];
      const short8 b1 = *(const short8*)&Ks[krow * 64 + (((lane >> 4) + 4) ^ (krow & 7)) * 8];
      f32x4 t = __builtin_amdgcn_mfma_f32_16x16x32_bf16(aq0, b0, vzero, 0, 0, 0);
      t = __builtin_amdgcn_mfma_f32_16x16x32_bf16(aq1, b1, t, 0, 0, 0);
      s[nr] = t;
    }

    // scale + mask + silu, write P (bf16) to per-wave LDS region, swizzled
#pragma unroll
    for (int rg = 0; rg < 4; ++rg) {
      const int row16 = ((lane >> 4) << 2) + rg;
      const unsigned int m0w = msk[(w * 16 + row16) * 2];
      const unsigned int m1w = msk[(w * 16 + row16) * 2 + 1];
#pragma unroll
      for (int nr = 0; nr < 4; ++nr) {
        const int col = nr * 16 + (lane & 15);
        const unsigned int word = (nr < 2) ? m0w : m1w;
        const float v = s[nr][rg] * 0.125f;
        const float p = ((word >> (col & 31)) & 1u) ? (v / (1.f + __expf(-v))) : 0.f;
        Ps[w * 1024 + row16 * 64 + (((col >> 3) ^ (row16 & 7)) << 3) + (col & 7)] = f2bf(p);
      }
    }

    // O += P @ V   (A-frags from Ps, B-frags from Vts; same-wave LDS RAW is ordered)
    const int prow = lane & 15;
    const short8 pa0 = *(const short8*)&Ps[w * 1024 + prow * 64 + (((lane >> 4)) ^ (prow & 7)) * 8];
    const short8 pa1 = *(const short8*)&Ps[w * 1024 + prow * 64 + (((lane >> 4) + 4) ^ (prow & 7)) * 8];
#pragma unroll
    for (int nr = 0; nr < 4; ++nr) {
      const int drow = nr * 16 + (lane & 15);
      const short8 v0 = *(const short8*)&Vts[drow * 64 + (((lane >> 4)) ^ (drow & 7)) * 8];
      const short8 v1 = *(const short8*)&Vts[drow * 64 + (((lane >> 4) + 4) ^ (drow & 7)) * 8];
      oacc[nr] = __builtin_amdgcn_mfma_f32_16x16x32_bf16(pa0, v0, oacc[nr], 0, 0, 0);
      oacc[nr] = __builtin_amdgcn_mfma_f32_16x16x32_bf16(pa1, v1, oacc[nr], 0, 0, 0);
    }
    __syncthreads();
  }

  // write attention output (bf16, token-major [4096][1024])
#pragma unroll
  for (int nr = 0; nr < 4; ++nr) {
#pragma unroll
    for (int rg = 0; rg < 4; ++rg) {
      const int row = qbase + w * 16 + ((lane >> 4) << 2) + rg;
      const int col = h * 64 + nr * 16 + (lane & 15);
      ao[(tok0 + row) * 1024 + col] = f2bf(oacc[nr][rg]);
    }
  }
}

// ---------- launcher ----------
extern "C" void kernel_launch(void* const* d_in, const int* in_sizes, int n_in,
                              void* d_out, int out_size, void* d_ws, size_t ws_size,
                              hipStream_t stream) {
  (void)in_sizes; (void)n_in; (void)out_size; (void)ws_size;
  const float* query = (const float*)d_in[0];
  const float* key   = (const float*)d_in[1];
  const float* value = (const float*)d_in[2];
  const int*   mask  = (const int*)d_in[3];
  const float* Wq = (const float*)d_in[4];
  const float* bq = (const float*)d_in[5];
  const float* Wk = (const float*)d_in[6];
  const float* bk = (const float*)d_in[7];
  const float* Wv = (const float*)d_in[8];
  const float* bv = (const float*)d_in[9];
  const float* Wo = (const float*)d_in[10];

  char* ws = (char*)d_ws;
  const size_t MB = 1024 * 1024;
  unsigned short* xq  = (unsigned short*)(ws + 0 * MB);   // 8 MB (reused by ao later)
  unsigned short* xk  = (unsigned short*)(ws + 8 * MB);   // 8 MB
  unsigned short* xv  = (unsigned short*)(ws + 16 * MB);  // 8 MB
  unsigned short* wqb = (unsigned short*)(ws + 24 * MB);  // 2 MB
  unsigned short* wkb = (unsigned short*)(ws + 26 * MB);  // 2 MB
  unsigned short* wvb = (unsigned short*)(ws + 28 * MB);  // 2 MB
  unsigned short* wob = (unsigned short*)(ws + 30 * MB);  // 2 MB
  unsigned short* qp  = (unsigned short*)(ws + 32 * MB);  // 8 MB
  unsigned short* kp  = (unsigned short*)(ws + 40 * MB);  // 8 MB
  unsigned short* vt  = (unsigned short*)(ws + 48 * MB);  // 8 MB
  unsigned int*   mb  = (unsigned int*)(ws + 56 * MB);    // 1 MB
  unsigned short* ao  = (unsigned short*)(ws + 0 * MB);   // reuse xq slot (free after proj)

  cvt_bf16<<<4096, 256, 0, stream>>>(query, xq, 1048576);
  cvt_bf16<<<4096, 256, 0, stream>>>(key,   xk, 1048576);
  cvt_bf16<<<4096, 256, 0, stream>>>(value, xv, 1048576);
  cvt_bf16<<<1024, 256, 0, stream>>>(Wq, wqb, 262144);
  cvt_bf16<<<1024, 256, 0, stream>>>(Wk, wkb, 262144);
  cvt_bf16<<<1024, 256, 0, stream>>>(Wv, wvb, 262144);
  cvt_bf16<<<1024, 256, 0, stream>>>(Wo, wob, 262144);
  pack_mask<<<32768, 256, 0, stream>>>(mask, (unsigned long long*)mb);

  proj_qkv<<<dim3(8, 32, 3), 256, 0, stream>>>(xq, xk, xv, wqb, wkb, wvb,
                                               bq, bk, bv, qp, kp, vt);
  attn_kernel<<<dim3(32, 16, 2), 256, 0, stream>>>(qp, kp, vt, mb, ao);
  out_proj<<<dim3(8, 32), 256, 0, stream>>>(ao, wob, (float*)d_out);
}

// Round 2
// 183.874 us; speedup vs baseline: 1.1733x; 1.1733x over previous
//
#include <hip/hip_runtime.h>
#include <hip/hip_bf16.h>

typedef __attribute__((ext_vector_type(4))) float f32x4;
typedef __attribute__((ext_vector_type(8))) short short8;

// ---------- helpers ----------
__device__ __forceinline__ unsigned short f2bf(float f) {
  unsigned int u = __float_as_uint(f);
  u += 0x7fffu + ((u >> 16) & 1u);   // RNE
  return (unsigned short)(u >> 16);
}

__device__ __forceinline__ void g2lds16(const void* g, void* l) {
  __builtin_amdgcn_global_load_lds(
      (const __attribute__((address_space(1))) void*)g,
      (__attribute__((address_space(3))) void*)l, 16, 0, 0);
}

// ---------- f32 -> bf16 convert ----------
__global__ __launch_bounds__(256) void cvt_bf16(const float* __restrict__ src,
                                                unsigned short* __restrict__ dst,
                                                int n4) {
  int i = blockIdx.x * 256 + threadIdx.x;
  if (i >= n4) return;
  const float4 v = ((const float4*)src)[i];
  ushort4 o;
  o.x = f2bf(v.x); o.y = f2bf(v.y); o.z = f2bf(v.z); o.w = f2bf(v.w);
  ((ushort4*)dst)[i] = o;
}

// ---------- mask -> bitmask ----------
__global__ __launch_bounds__(256) void pack_mask(const int* __restrict__ mask,
                                                 unsigned long long* __restrict__ mb) {
  int i = blockIdx.x * 256 + threadIdx.x;
  unsigned long long bits = __ballot(mask[i] != 0);
  if ((threadIdx.x & 63) == 0) mb[i >> 6] = bits;
}

// ---------- 128x128 tile bf16 GEMM: C[M,N] = A[M,K] @ B[N,K]^T (+bias)*cscale ----
// BIAS_MODE: 0 none, 1 per-col(N), 2 per-row(M).  OUT_BF16: 1 bf16, 0 f32.
template <int BIAS_MODE, int OUT_BF16>
__device__ __forceinline__ void gemm_tile(
    unsigned short* __restrict__ As, unsigned short* __restrict__ Bs,
    const unsigned short* __restrict__ A, const unsigned short* __restrict__ B,
    const float* __restrict__ bias, void* __restrict__ Cp,
    const int N, const int K, const int m0, const int n0, const float cscale) {
  const int tid  = (int)threadIdx.x;
  const int lane = tid & 63;
  const int wm   = tid >> 7;
  const int wn   = (tid >> 6) & 1;

  const f32x4 vzero = {0.f, 0.f, 0.f, 0.f};
  f32x4 acc[4][4];
#pragma unroll
  for (int mr = 0; mr < 4; ++mr)
#pragma unroll
    for (int nr = 0; nr < 4; ++nr) acc[mr][nr] = vzero;

  for (int k0 = 0; k0 < K; k0 += 64) {
    // stage A,B tiles (128x64 bf16 each) via async global->LDS, width 16,
    // source pre-swizzled so LDS holds XOR(row&7)-swizzled 16B chunks.
#pragma unroll
    for (int i = 0; i < 4; ++i) {
      const int idx = i * 256 + tid;
      const int r = idx >> 3;
      const int c = idx & 7;
      const int koff = k0 + ((c ^ (r & 7)) << 3);
      g2lds16(A + (size_t)(m0 + r) * K + koff, &As[(i * 256 + (tid & 192)) * 8]);
      g2lds16(B + (size_t)(n0 + r) * K + koff, &Bs[(i * 256 + (tid & 192)) * 8]);
    }
    __syncthreads();
#pragma unroll
    for (int kk = 0; kk < 2; ++kk) {
      short8 af[4], bf[4];
#pragma unroll
      for (int mr = 0; mr < 4; ++mr) {
        const int row = wm * 64 + mr * 16 + (lane & 15);
        const int ch = (kk * 4 + (lane >> 4)) ^ (row & 7);
        af[mr] = *(const short8*)&As[row * 64 + ch * 8];
      }
#pragma unroll
      for (int nr = 0; nr < 4; ++nr) {
        const int row = wn * 64 + nr * 16 + (lane & 15);
        const int ch = (kk * 4 + (lane >> 4)) ^ (row & 7);
        bf[nr] = *(const short8*)&Bs[row * 64 + ch * 8];
      }
#pragma unroll
      for (int mr = 0; mr < 4; ++mr)
#pragma unroll
        for (int nr = 0; nr < 4; ++nr)
          acc[mr][nr] = __builtin_amdgcn_mfma_f32_16x16x32_bf16(af[mr], bf[nr],
                                                                acc[mr][nr], 0, 0, 0);
    }
    __syncthreads();
  }

#pragma unroll
  for (int mr = 0; mr < 4; ++mr) {
#pragma unroll
    for (int nr = 0; nr < 4; ++nr) {
#pragma unroll
      for (int rg = 0; rg < 4; ++rg) {
        const int row = m0 + wm * 64 + mr * 16 + ((lane >> 4) << 2) + rg;
        const int col = n0 + wn * 64 + nr * 16 + (lane & 15);
        float v = acc[mr][nr][rg];
        if (BIAS_MODE == 1) v += bias[col];
        if (BIAS_MODE == 2) v += bias[row];
        v *= cscale;
        if (OUT_BF16) ((unsigned short*)Cp)[(size_t)row * N + col] = f2bf(v);
        else          ((float*)Cp)[(size_t)row * N + col] = v;
      }
    }
  }
}

#define QSCALE 0.18033688011112042f  /* 0.125 * log2(e) */
#define LN2    0.6931471805599453f

// qp = (xq@Wq^T+bq)*QSCALE ; kp = xk@Wk^T+bk ; vt = Wv@xv^T+bv  (vt [1024 d'][4096 tok])
__global__ __launch_bounds__(256) void proj_qkv(
    const unsigned short* __restrict__ xq, const unsigned short* __restrict__ xk,
    const unsigned short* __restrict__ xv,
    const unsigned short* __restrict__ wq, const unsigned short* __restrict__ wk,
    const unsigned short* __restrict__ wv,
    const float* __restrict__ bq, const float* __restrict__ bk,
    const float* __restrict__ bv,
    unsigned short* __restrict__ qp, unsigned short* __restrict__ kp,
    unsigned short* __restrict__ vt) {
  __shared__ unsigned short As[128 * 64];
  __shared__ unsigned short Bs[128 * 64];
  const int z = blockIdx.z;
  if (z == 0) {
    gemm_tile<1, 1>(As, Bs, xq, wq, bq, qp, 1024, 1024, blockIdx.y * 128, blockIdx.x * 128, QSCALE);
  } else if (z == 1) {
    gemm_tile<1, 1>(As, Bs, xk, wk, bk, kp, 1024, 1024, blockIdx.y * 128, blockIdx.x * 128, 1.0f);
  } else {
    gemm_tile<2, 1>(As, Bs, wv, xv, bv, vt, 4096, 1024, blockIdx.x * 128, blockIdx.y * 128, 1.0f);
  }
}

__global__ __launch_bounds__(256) void out_proj(
    const unsigned short* __restrict__ ao, const unsigned short* __restrict__ wo,
    float* __restrict__ out) {
  __shared__ unsigned short As[128 * 64];
  __shared__ unsigned short Bs[128 * 64];
  gemm_tile<0, 0>(As, Bs, ao, wo, nullptr, out, 1024, 1024, blockIdx.y * 128, blockIdx.x * 128, 1.0f);
}

// ---------- fused silu-attention ----------
// grid (32 qblk, 16 h, 2 b), 256 thr (4 waves x 16 q-rows). K/V tiles 64x64,
// double-buffered, 1 barrier per k-tile. Mask read straight from global (L2).
__global__ __launch_bounds__(256) void attn_kernel(
    const unsigned short* __restrict__ qp, const unsigned short* __restrict__ kp,
    const unsigned short* __restrict__ vt, const unsigned long long* __restrict__ mb,
    unsigned short* __restrict__ ao) {
  __shared__ unsigned short Ks[2][64 * 64];
  __shared__ unsigned short Vts[2][64 * 64];
  __shared__ unsigned short Ps[4 * 16 * 64];

  const int tid  = (int)threadIdx.x;
  const int lane = tid & 63;
  const int w    = tid >> 6;
  const int hi   = lane >> 4;
  const int c    = lane & 15;
  const int qbase = blockIdx.x * 64;
  const int h = blockIdx.y;
  const int b = blockIdx.z;
  const size_t tok0 = (size_t)b * 2048;

  // Q fragments held in registers for the whole block
  const int qr = qbase + w * 16 + c;
  const unsigned short* qptr = qp + (tok0 + qr) * 1024 + h * 64 + (hi << 3);
  const short8 aq0 = *(const short8*)qptr;
  const short8 aq1 = *(const short8*)(qptr + 32);

  // per-lane mask base: rows (qbase + w*16 + 4*hi + rg), word stride 32 per row
  const unsigned long long* mql = mb + ((tok0 + qbase + w * 16 + hi * 4)) * 32;

  const f32x4 vzero = {0.f, 0.f, 0.f, 0.f};
  f32x4 oacc[4];
#pragma unroll
  for (int nr = 0; nr < 4; ++nr) oacc[nr] = vzero;

  // staging indices (lane-invariant parts)
  const int sidx0 = tid;          // i = 0
  const int sidx1 = 256 + tid;    // i = 1

  // prologue: stage tile 0 into buf 0
  {
#pragma unroll
    for (int i = 0; i < 2; ++i) {
      const int idx = i * 256 + tid;
      const int r = idx >> 3;
      const int cc = idx & 7;
      const int cs = (cc ^ (r & 7)) << 3;
      g2lds16(kp + (tok0 + r) * 1024 + h * 64 + cs, &Ks[0][(i * 256 + (tid & 192)) * 8]);
      g2lds16(vt + (size_t)(h * 64 + r) * 4096 + tok0 + cs, &Vts[0][(i * 256 + (tid & 192)) * 8]);
    }
  }
  __syncthreads();

  int buf = 0;
  for (int kt = 0; kt < 32; ++kt) {
    // issue next tile's loads into buf^1 (overlap with compute; barrier drains)
    if (kt < 31) {
#pragma unroll
      for (int i = 0; i < 2; ++i) {
        const int idx = i * 256 + tid;
        const int r = idx >> 3;
        const int cc = idx & 7;
        const int cs = (cc ^ (r & 7)) << 3;
        g2lds16(kp + (tok0 + (kt + 1) * 64 + r) * 1024 + h * 64 + cs,
                &Ks[buf ^ 1][(i * 256 + (tid & 192)) * 8]);
        g2lds16(vt + (size_t)(h * 64 + r) * 4096 + tok0 + (kt + 1) * 64 + cs,
                &Vts[buf ^ 1][(i * 256 + (tid & 192)) * 8]);
      }
    }

    // mask words for this lane's 4 q-rows (global, L2-resident, broadcast)
    unsigned long long mrow[4];
#pragma unroll
    for (int rg = 0; rg < 4; ++rg) mrow[rg] = mql[rg * 32 + kt];

    // S' = Q' @ K^T   (Q pre-scaled by 0.125*log2e)
    f32x4 s[4];
    __builtin_amdgcn_s_setprio(1);
#pragma unroll
    for (int nr = 0; nr < 4; ++nr) {
      const int krow = nr * 16 + c;
      const short8 b0 = *(const short8*)&Ks[buf][krow * 64 + ((hi) ^ (krow & 7)) * 8];
      const short8 b1 = *(const short8*)&Ks[buf][krow * 64 + ((hi + 4) ^ (krow & 7)) * 8];
      f32x4 t = __builtin_amdgcn_mfma_f32_16x16x32_bf16(aq0, b0, vzero, 0, 0, 0);
      t = __builtin_amdgcn_mfma_f32_16x16x32_bf16(aq1, b1, t, 0, 0, 0);
      s[nr] = t;
    }
    __builtin_amdgcn_s_setprio(0);

    // mask + silu (exp2 domain) + pack to bf16, write P to per-wave LDS region
#pragma unroll
    for (int rg = 0; rg < 4; ++rg) {
      const int row16 = (hi << 2) + rg;
      const unsigned long long ms = mrow[rg] >> c;
#pragma unroll
      for (int nr = 0; nr < 4; ++nr) {
        float sv = s[nr][rg];
        sv = ((unsigned int)(ms >> (nr * 16)) & 1u) ? sv : 0.f;
        // silu(ln2*s') / ln2 = s' * sigmoid2(s'),  sigmoid2 = 1/(1+2^-s')
        const float p = sv * __builtin_amdgcn_rcpf(1.f + __builtin_amdgcn_exp2f(-sv));
        const unsigned int u = __float_as_uint(p) + 0x8000u;  // round-half-up to bf16
        const int col = nr * 16 + c;
        Ps[w * 1024 + row16 * 64 + (((col >> 3) ^ (row16 & 7)) << 3) + (col & 7)] =
            (unsigned short)(u >> 16);
      }
    }

    // O += P @ V   (same-wave LDS RAW ordered by lgkmcnt)
    const short8 pa0 = *(const short8*)&Ps[w * 1024 + c * 64 + ((hi) ^ (c & 7)) * 8];
    const short8 pa1 = *(const short8*)&Ps[w * 1024 + c * 64 + ((hi + 4) ^ (c & 7)) * 8];
    __builtin_amdgcn_s_setprio(1);
#pragma unroll
    for (int nr = 0; nr < 4; ++nr) {
      const int drow = nr * 16 + c;
      const short8 v0 = *(const short8*)&Vts[buf][drow * 64 + ((hi) ^ (drow & 7)) * 8];
      const short8 v1 = *(const short8*)&Vts[buf][drow * 64 + ((hi + 4) ^ (drow & 7)) * 8];
      oacc[nr] = __builtin_amdgcn_mfma_f32_16x16x32_bf16(pa0, v0, oacc[nr], 0, 0, 0);
      oacc[nr] = __builtin_amdgcn_mfma_f32_16x16x32_bf16(pa1, v1, oacc[nr], 0, 0, 0);
    }
    __builtin_amdgcn_s_setprio(0);

    __syncthreads();   // drains next-tile global_load_lds + syncs Ps reuse
    buf ^= 1;
  }

  // write attention output * ln2 (bf16, token-major [4096][1024])
#pragma unroll
  for (int nr = 0; nr < 4; ++nr) {
#pragma unroll
    for (int rg = 0; rg < 4; ++rg) {
      const int row = qbase + w * 16 + (hi << 2) + rg;
      const int col = h * 64 + nr * 16 + c;
      ao[(tok0 + row) * 1024 + col] = f2bf(oacc[nr][rg] * LN2);
    }
  }
}

// ---------- launcher ----------
extern "C" void kernel_launch(void* const* d_in, const int* in_sizes, int n_in,
                              void* d_out, int out_size, void* d_ws, size_t ws_size,
                              hipStream_t stream) {
  (void)in_sizes; (void)n_in; (void)out_size; (void)ws_size;
  const float* query = (const float*)d_in[0];
  const float* key   = (const float*)d_in[1];
  const float* value = (const float*)d_in[2];
  const int*   mask  = (const int*)d_in[3];
  const float* Wq = (const float*)d_in[4];
  const float* bq = (const float*)d_in[5];
  const float* Wk = (const float*)d_in[6];
  const float* bk = (const float*)d_in[7];
  const float* Wv = (const float*)d_in[8];
  const float* bv = (const float*)d_in[9];
  const float* Wo = (const float*)d_in[10];

  char* ws = (char*)d_ws;
  const size_t MB = 1024 * 1024;
  unsigned short* xq  = (unsigned short*)(ws + 0 * MB);   // 8 MB (reused by ao later)
  unsigned short* xk  = (unsigned short*)(ws + 8 * MB);   // 8 MB
  unsigned short* xv  = (unsigned short*)(ws + 16 * MB);  // 8 MB
  unsigned short* wqb = (unsigned short*)(ws + 24 * MB);  // 2 MB
  unsigned short* wkb = (unsigned short*)(ws + 26 * MB);  // 2 MB
  unsigned short* wvb = (unsigned short*)(ws + 28 * MB);  // 2 MB
  unsigned short* wob = (unsigned short*)(ws + 30 * MB);  // 2 MB
  unsigned short* qp  = (unsigned short*)(ws + 32 * MB);  // 8 MB
  unsigned short* kp  = (unsigned short*)(ws + 40 * MB);  // 8 MB
  unsigned short* vt  = (unsigned short*)(ws + 48 * MB);  // 8 MB
  unsigned long long* mbq = (unsigned long long*)(ws + 56 * MB); // 1 MB
  unsigned short* ao  = (unsigned short*)(ws + 0 * MB);   // reuse xq slot

  cvt_bf16<<<4096, 256, 0, stream>>>(query, xq, 1048576);
  cvt_bf16<<<4096, 256, 0, stream>>>(key,   xk, 1048576);
  cvt_bf16<<<4096, 256, 0, stream>>>(value, xv, 1048576);
  cvt_bf16<<<1024, 256, 0, stream>>>(Wq, wqb, 262144);
  cvt_bf16<<<1024, 256, 0, stream>>>(Wk, wkb, 262144);
  cvt_bf16<<<1024, 256, 0, stream>>>(Wv, wvb, 262144);
  cvt_bf16<<<1024, 256, 0, stream>>>(Wo, wob, 262144);
  pack_mask<<<32768, 256, 0, stream>>>(mask, mbq);

  proj_qkv<<<dim3(8, 32, 3), 256, 0, stream>>>(xq, xk, xv, wqb, wkb, wvb,
                                               bq, bk, bv, qp, kp, vt);
  attn_kernel<<<dim3(32, 16, 2), 256, 0, stream>>>(qp, kp, vt, mbq, ao);
  out_proj<<<dim3(8, 32), 256, 0, stream>>>(ao, wob, (float*)d_out);
}